// Round 7
// baseline (178.011 us; speedup 1.0000x reference)
//
#include <hip/hip_runtime.h>
#include <hip/hip_bf16.h>
#include <hip/hip_fp16.h>
#include <math.h>

#define IN_CH   128
#define OUT_CH  32
#define HEADS   2
#define HC      (HEADS * OUT_CH)   // 64
#define NEG_SLOPE 0.2f

#define NODE_TILE 64
// Wt AND Xs: NO pad (256 B rows) + XOR chunk swizzle:
//   Wt: half index = col*128 + ((k>>3) ^ ((col>>3)&7))*8 + (k&7)
//   Xs: half index = row*128 + ((k>>3) ^ (row&7))*8 + (k&7)
// Both reads hit 8 distinct 4-bank groups across the wave -> conflict-free.

#define DEG_STRIDE 16    // one counter per 64 B cache line: R5 showed the
                         // atomic phase pinned at 7.7 atomics/cyc device-wide,
                         // insensitive to ILP (R3) and occupancy (R4/R5) ->
                         // line-contention at the coherence point (16
                         // counters/line, ~68 atomics/line). Spread them.

#define BIN_CAP 64       // max deg: Poisson(17), P(>=64) ~ 1e-19/node — safe

typedef _Float16 h2_t __attribute__((ext_vector_type(2)));
union V16 { int4 v; h2_t h[4]; };

__device__ __forceinline__ float fdot2(h2_t a, h2_t b, float c) {
#if __has_builtin(__builtin_amdgcn_fdot2)
    return __builtin_amdgcn_fdot2(a, b, c, false);
#else
    return c + (float)a.x * (float)b.x + (float)a.y * (float)b.y;
#endif
}

// ---------------------------------------------------------------------------
// Kernel 1: hist+fill fused, ZERO LDS, ILP=1 (3321 blocks -> max TLP).
// rk = atomicAdd(&deg[d*16]) on line-private counters; direct bins4 store.
// ---------------------------------------------------------------------------
__global__ __launch_bounds__(256) void hist_fill_kernel(
    const int* __restrict__ src, const int* __restrict__ dst,
    int* __restrict__ deg, int* __restrict__ bins4,
    int n_edges, int n_total)
{
    int e = blockIdx.x * blockDim.x + threadIdx.x;
    if (e >= n_total) return;
    int s, d;
    if (e < n_edges) { s = src[e]; d = dst[e]; }
    else             { s = d = e - n_edges; }
    int rk = atomicAdd(&deg[d * DEG_STRIDE], 1);
    if (rk < BIN_CAP) bins4[(size_t)d * BIN_CAP + rk] = s;
}

// ---------------------------------------------------------------------------
// Kernel 2: pure GEMM h = x@W (f16 LDS + v_dot2_f32_f16, 2 nodes/thread)
// + fused per-node logits. 782 blocks, 32 KB LDS (swizzled, conflict-free).
// ---------------------------------------------------------------------------
__global__ __launch_bounds__(256) void gemm_logits_kernel(
    const float* __restrict__ x, const float* __restrict__ W,
    const float* __restrict__ a_src, const float* __restrict__ a_dst,
    __half* __restrict__ h, float* __restrict__ alpha_s, float* __restrict__ alpha_d,
    int n_nodes)
{
    const int tid = threadIdx.x;

    __shared__ _Float16 Wt[HC * IN_CH];        // [col][k] swizzled, 16 KB
    __shared__ _Float16 Xs[NODE_TILE * IN_CH]; // [node][k] swizzled, 16 KB

    const int node0 = blockIdx.x * NODE_TILE;

    const float4* W4 = (const float4*)W;
    #pragma unroll
    for (int i = 0; i < 8; ++i) {
        int idx4 = tid + i * 256;
        int k  = idx4 >> 4;        // W row = k index, 0..127
        int c4 = idx4 & 15;        // 16 float4 per W row (64 cols)
        float4 v = W4[idx4];
        int chunk = k >> 3, klo = k & 7;
        _Float16 vals[4] = {(_Float16)v.x, (_Float16)v.y, (_Float16)v.z, (_Float16)v.w};
        #pragma unroll
        for (int r = 0; r < 4; ++r) {
            int col = c4 * 4 + r;
            int gc  = (col >> 3) & 7;
            Wt[col * IN_CH + ((chunk ^ gc) << 3) + klo] = vals[r];
        }
    }

    const float4* X4 = (const float4*)x;
    #pragma unroll
    for (int i = 0; i < 8; ++i) {
        int idx4 = tid + i * 256;
        int r = idx4 >> 5, c4 = idx4 & 31;   // k = 4*c4 .. 4*c4+3
        int node = node0 + r;
        float4 v = make_float4(0.f, 0.f, 0.f, 0.f);
        if (node < n_nodes) v = X4[(size_t)node * (IN_CH / 4) + c4];
        _Float16 hv[4] = {(_Float16)v.x, (_Float16)v.y, (_Float16)v.z, (_Float16)v.w};
        int ofs = r * IN_CH + (((c4 >> 1) ^ (r & 7)) << 3) + (c4 & 1) * 4;
        *(int2*)&Xs[ofs] = *(int2*)hv;       // 8 B aligned
    }
    __syncthreads();

    const int n    = tid >> 3;        // 0..31  (nodes n and n+32)
    const int g    = tid & 7;
    const int col0 = g * 8;
    const int head = col0 >> 5;
    const int c0   = col0 & 31;

    float accA[8] = {0,0,0,0,0,0,0,0};
    float accB[8] = {0,0,0,0,0,0,0,0};
    const _Float16* xa = &Xs[n * IN_CH];
    const _Float16* xb = &Xs[(n + 32) * IN_CH];   // (n+32)&7 == n&7: same xor key
    const int xkey = n & 7;

    for (int k0 = 0; k0 < IN_CH; k0 += 8) {
        const int chunk = k0 >> 3;
        const int xofs  = ((chunk ^ xkey) << 3);
        V16 va, vb;
        va.v = *(const int4*)&xa[xofs];
        vb.v = *(const int4*)&xb[xofs];
        // swizzled chunk base for this k-step (one xor+shl per iteration)
        const _Float16* wbase = &Wt[col0 * IN_CH + ((chunk ^ g) << 3)];
        #pragma unroll
        for (int j = 0; j < 8; ++j) {
            V16 w;
            w.v = *(const int4*)&wbase[j * IN_CH];   // j*256 B immediate
            float a = accA[j], b = accB[j];
            a = fdot2(w.h[0], va.h[0], a); b = fdot2(w.h[0], vb.h[0], b);
            a = fdot2(w.h[1], va.h[1], a); b = fdot2(w.h[1], vb.h[1], b);
            a = fdot2(w.h[2], va.h[2], a); b = fdot2(w.h[2], vb.h[2], b);
            a = fdot2(w.h[3], va.h[3], a); b = fdot2(w.h[3], vb.h[3], b);
            accA[j] = a; accB[j] = b;
        }
    }

    float asr[8], adr[8];
    #pragma unroll
    for (int j = 0; j < 8; ++j) {
        asr[j] = a_src[head * OUT_CH + c0 + j];
        adr[j] = a_dst[head * OUT_CH + c0 + j];
    }

    #pragma unroll
    for (int half = 0; half < 2; ++half) {
        const float* acc = half ? accB : accA;
        const int node = node0 + n + half * 32;
        if (node < n_nodes) {
            unsigned u[8];
            #pragma unroll
            for (int j = 0; j < 8; ++j) u[j] = __half_as_ushort(__float2half_rn(acc[j]));
            int4 v = make_int4((int)(u[0] | (u[1] << 16)), (int)(u[2] | (u[3] << 16)),
                               (int)(u[4] | (u[5] << 16)), (int)(u[6] | (u[7] << 16)));
            *(int4*)&h[(size_t)node * HC + col0] = v;
        }
        float ps = 0.f, pd = 0.f;
        #pragma unroll
        for (int j = 0; j < 8; ++j) { ps += acc[j] * asr[j]; pd += acc[j] * adr[j]; }
        ps += __shfl_xor(ps, 1); ps += __shfl_xor(ps, 2);
        pd += __shfl_xor(pd, 1); pd += __shfl_xor(pd, 2);
        if ((g & 3) == 0 && node < n_nodes) {
            alpha_s[node * HEADS + head] = ps;
            alpha_d[node * HEADS + head] = pd;
        }
    }
}

// ---------------------------------------------------------------------------
// Kernel 3: one wave per node.
// PRELOAD (parallel): lane L reads src idx L (coalesced), gathers
// alpha_s2[s] (64 random 8 B L2 hits in flight), computes p0/p1 =
// exp(leakyrelu(...)); f16-rounds them; butterfly-reduces lsum ONCE; stages
// {src, p01:f16x2} to this wave's LDS slot (one ds_write_b64).
// INNER LOOP: FOUR edges per wave-instruction. Lane L: subgroup
// q=L>>4 owns edge slot i+4j+q; channel quad c=L&15 (8 B of the 128 B
// h-row). Per 4 edges: 1 ds_read_b64 (4-addr bcast) + 1
// global_load_dwordx2 + ~12 VALU. Epilogue: shfl_xor(16)+shfl_xor(32)
// combine, float4 out write (16 lanes x 16 B = 256 B coalesced).
// Rounds of 8 slots (p=0 beyond cnt -> branch-free).
// ---------------------------------------------------------------------------
__global__ __launch_bounds__(256) void node_gather_kernel(
    const int* __restrict__ bins4, const int* __restrict__ deg,
    const float* __restrict__ alpha_s, const float* __restrict__ alpha_d,
    const __half* __restrict__ h, const float* __restrict__ bias,
    float* __restrict__ out, int n_nodes)
{
    __shared__ int2 stage[4][BIN_CAP];   // 2 KB; one 64-slot row per wave
    const int w = threadIdx.x >> 6;
    int node = blockIdx.x * 4 + w;
    if (node >= n_nodes) return;
    const int lane = threadIdx.x & 63;
    int cnt = deg[node * DEG_STRIDE];
    if (cnt > BIN_CAP) cnt = BIN_CAP;

    float2 adn = ((const float2*)alpha_d)[node];

    int sreg = 0;
    float p0 = 0.f, p1 = 0.f;
    if (lane < cnt) {
        sreg = bins4[(size_t)node * BIN_CAP + lane];
        float2 a2 = ((const float2*)alpha_s)[sreg];
        float v0 = a2.x + adn.x;
        float v1 = a2.y + adn.y;
        v0 = (v0 > 0.f) ? v0 : NEG_SLOPE * v0;
        v1 = (v1 > 0.f) ? v1 : NEG_SLOPE * v1;
        p0 = __expf(v0);   // shift-invariant softmax; logits O(8): no overflow
        p1 = __expf(v1);
    }

    // f16-round p (so lsum matches the accumulated values exactly)
    unsigned u0 = __half_as_ushort(__float2half_rn(p0));
    unsigned u1 = __half_as_ushort(__float2half_rn(p1));
    float q0 = __half2float(__ushort_as_half((unsigned short)u0));
    float q1 = __half2float(__ushort_as_half((unsigned short)u1));

    // lsum once per node: butterfly over 64 lanes
    #pragma unroll
    for (int off = 1; off < 64; off <<= 1) {
        q0 += __shfl_xor(q0, off);
        q1 += __shfl_xor(q1, off);
    }

    // stage records (one ds_write_b64 per wave)
    stage[w][lane] = make_int2(sreg, (int)((u1 << 16) | u0));
    // same-wave LDS write->read ordering: compiler inserts lgkmcnt wait

    const int q = lane >> 4;                        // edge subgroup 0..3
    const int c = lane & 15;                        // channel quad: ch 4c..4c+3
    const unsigned hshift = (unsigned)(c >> 3) << 4;   // head select: 0 or 16
    const unsigned laneofs = (unsigned)c << 3;      // byte offset in h row
    const char* hb = (const char*)h;

    float a0 = 0.f, a1 = 0.f, a2v = 0.f, a3 = 0.f;
    for (int i = 0; i < cnt; i += 8) {
        #pragma unroll
        for (int j = 0; j < 2; ++j) {
            int2 rec = stage[w][i + 4 * j + q];     // 4-addr 16-lane bcast
            unsigned ofs = ((unsigned)rec.x << 7) + laneofs; // row = 128 B
            int2 hv = *(const int2*)(hb + ofs);     // 4 halves
            __half2 hlo = *(__half2*)&hv.x;
            __half2 hhi = *(__half2*)&hv.y;
            float pj = __half2float(__ushort_as_half(
                           (unsigned short)(((unsigned)rec.y) >> hshift)));
            float2 flo = __half22float2(hlo);
            float2 fhi = __half22float2(hhi);
            a0  += pj * flo.x;                      // p=0 beyond cnt
            a1  += pj * flo.y;
            a2v += pj * fhi.x;
            a3  += pj * fhi.y;
        }
    }
    // combine the 4 edge-subsets across subgroups
    a0  += __shfl_xor(a0, 16);  a0  += __shfl_xor(a0, 32);
    a1  += __shfl_xor(a1, 16);  a1  += __shfl_xor(a1, 32);
    a2v += __shfl_xor(a2v, 16); a2v += __shfl_xor(a2v, 32);
    a3  += __shfl_xor(a3, 16);  a3  += __shfl_xor(a3, 32);

    if (lane < 16) {
        const float lsum = (c >> 3) ? q1 : q0;
        const float inv = 1.f / (lsum + 1e-16f);
        float4 b4 = ((const float4*)bias)[c];
        float4 o;
        o.x = a0  * inv + b4.x;
        o.y = a1  * inv + b4.y;
        o.z = a2v * inv + b4.z;
        o.w = a3  * inv + b4.w;
        ((float4*)out)[(size_t)node * (HC / 4) + c] = o;
    }
}

// ---------------------------------------------------------------------------
extern "C" void kernel_launch(void* const* d_in, const int* in_sizes, int n_in,
                              void* d_out, int out_size, void* d_ws, size_t ws_size,
                              hipStream_t stream)
{
    const float* x      = (const float*)d_in[0];
    const int*   ei     = (const int*)d_in[1];
    const float* W      = (const float*)d_in[2];
    const float* a_src  = (const float*)d_in[3];
    const float* a_dst  = (const float*)d_in[4];
    const float* bias   = (const float*)d_in[5];
    float* out = (float*)d_out;

    const int n_nodes = in_sizes[0] / IN_CH;        // 50000
    const int n_edges = in_sizes[1] / 2;            // 800000
    const int n_total = n_edges + n_nodes;

    const int* src = ei;             // row 0
    const int* dst = ei + n_edges;   // row 1

    // workspace layout (~23 MB of 268 MB)
    __half* h      = (__half*)d_ws;                              // n*64 f16
    float* alpha_s = (float*)(h + (size_t)n_nodes * HC);         // n*2
    float* alpha_d = alpha_s + (size_t)n_nodes * HEADS;          // n*2
    int* deg       = (int*)(alpha_d + (size_t)n_nodes * HEADS);  // n*16 (line-strided)
    int* bins4     = deg + (size_t)n_nodes * DEG_STRIDE;         // n*64 int

    const int hist_blocks = (n_total + 255) / 256;
    const int gemm_blocks = (n_nodes + NODE_TILE - 1) / NODE_TILE;

    // 1. zero strided deg counters (3.2 MB, ~1 us)
    hipMemsetAsync(deg, 0, (size_t)n_nodes * DEG_STRIDE * sizeof(int), stream);

    // 2. hist+fill fused, zero-LDS, line-private counters
    hist_fill_kernel<<<hist_blocks, 256, 0, stream>>>(
        src, dst, deg, bins4, n_edges, n_total);

    // 3. pure GEMM + logits
    gemm_logits_kernel<<<gemm_blocks, 256, 0, stream>>>(
        x, W, a_src, a_dst, h, alpha_s, alpha_d, n_nodes);

    // 4. gather: 4-edge staged-broadcast inner loop; + bias
    int ng_blocks = (n_nodes + 3) / 4;
    node_gather_kernel<<<ng_blocks, 256, 0, stream>>>(
        bins4, deg, alpha_s, alpha_d, h, bias, out, n_nodes);
}

// Round 8
// 155.473 us; speedup vs baseline: 1.1450x; 1.1450x over previous
//
#include <hip/hip_runtime.h>
#include <hip/hip_bf16.h>
#include <hip/hip_fp16.h>
#include <math.h>

#define IN_CH   128
#define OUT_CH  32
#define HEADS   2
#define HC      (HEADS * OUT_CH)   // 64
#define NEG_SLOPE 0.2f

#define NODE_TILE 64
// Wt AND Xs: NO pad (256 B rows) + XOR chunk swizzle:
//   Wt: half index = col*128 + ((k>>3) ^ ((col>>3)&7))*8 + (k&7)
//   Xs: half index = row*128 + ((k>>3) ^ (row&7))*8 + (k&7)
// Both reads hit 8 distinct 4-bank groups across the wave -> conflict-free.
// 32 KB total.

#define BIN_CAP 64       // max deg: Poisson(17), P(>=64) ~ 1e-19/node — safe

// Atomic phase facts (R2-R7): 850K random atomicAdd-with-return ~= 44 us
// regardless of ILP/occupancy/line-layout = ~19 G atomics/s hardware wall.
// Scattered stores and atomics ADD when in one kernel (R4: 44+23); GEMM's
// LDS/VALU rides free inside the atomic window (R1/R2). Hence: mixed
// (gemm || hist->coalesced rank) + separate fill + gather.

typedef _Float16 h2_t __attribute__((ext_vector_type(2)));
union V16 { int4 v; h2_t h[4]; };

__device__ __forceinline__ float fdot2(h2_t a, h2_t b, float c) {
#if __has_builtin(__builtin_amdgcn_fdot2)
    return __builtin_amdgcn_fdot2(a, b, c, false);
#else
    return c + (float)a.x * (float)b.x + (float)a.y * (float)b.y;
#endif
}

// ---------------------------------------------------------------------------
// Kernel 1 (mixed grid): blocks [0, gemm_blocks) = GEMM h = x@W (f16 LDS +
// v_dot2_f32_f16, 2 nodes/thread) + fused logits. Blocks [gemm_blocks, ...)
// = hist: rank[e] = atomicAdd(deg[d]) -> coalesced rank write only.
// ---------------------------------------------------------------------------
__global__ __launch_bounds__(256) void gemm_hist_kernel(
    const float* __restrict__ x, const float* __restrict__ W,
    const float* __restrict__ a_src, const float* __restrict__ a_dst,
    __half* __restrict__ h, float* __restrict__ alpha_s, float* __restrict__ alpha_d,
    const int* __restrict__ dst, int* __restrict__ deg, int* __restrict__ rank,
    int n_nodes, int n_edges, int n_total, int gemm_blocks)
{
    const int tid = threadIdx.x;

    if (blockIdx.x >= gemm_blocks) {
        // ---- hist role (no LDS touched; TA-pipe bound, VALU/LDS idle) ----
        int e = (blockIdx.x - gemm_blocks) * blockDim.x + tid;
        if (e < n_total) {
            int d = (e < n_edges) ? dst[e] : (e - n_edges);
            rank[e] = atomicAdd(&deg[d], 1);
        }
        return;
    }

    // ---- gemm role ----
    __shared__ _Float16 Wt[HC * IN_CH];        // [col][k] swizzled, 16 KB
    __shared__ _Float16 Xs[NODE_TILE * IN_CH]; // [node][k] swizzled, 16 KB

    const int node0 = blockIdx.x * NODE_TILE;

    const float4* W4 = (const float4*)W;
    #pragma unroll
    for (int i = 0; i < 8; ++i) {
        int idx4 = tid + i * 256;
        int k  = idx4 >> 4;        // W row = k index, 0..127
        int c4 = idx4 & 15;        // 16 float4 per W row (64 cols)
        float4 v = W4[idx4];
        int chunk = k >> 3, klo = k & 7;
        _Float16 vals[4] = {(_Float16)v.x, (_Float16)v.y, (_Float16)v.z, (_Float16)v.w};
        #pragma unroll
        for (int r = 0; r < 4; ++r) {
            int col = c4 * 4 + r;
            int gc  = (col >> 3) & 7;
            Wt[col * IN_CH + ((chunk ^ gc) << 3) + klo] = vals[r];
        }
    }

    const float4* X4 = (const float4*)x;
    #pragma unroll
    for (int i = 0; i < 8; ++i) {
        int idx4 = tid + i * 256;
        int r = idx4 >> 5, c4 = idx4 & 31;   // k = 4*c4 .. 4*c4+3
        int node = node0 + r;
        float4 v = make_float4(0.f, 0.f, 0.f, 0.f);
        if (node < n_nodes) v = X4[(size_t)node * (IN_CH / 4) + c4];
        _Float16 hv[4] = {(_Float16)v.x, (_Float16)v.y, (_Float16)v.z, (_Float16)v.w};
        int ofs = r * IN_CH + (((c4 >> 1) ^ (r & 7)) << 3) + (c4 & 1) * 4;
        *(int2*)&Xs[ofs] = *(int2*)hv;       // 8 B aligned
    }
    __syncthreads();

    const int n    = tid >> 3;        // 0..31  (nodes n and n+32)
    const int g    = tid & 7;
    const int col0 = g * 8;
    const int head = col0 >> 5;
    const int c0   = col0 & 31;

    float accA[8] = {0,0,0,0,0,0,0,0};
    float accB[8] = {0,0,0,0,0,0,0,0};
    const _Float16* xa = &Xs[n * IN_CH];
    const _Float16* xb = &Xs[(n + 32) * IN_CH];   // (n+32)&7 == n&7: same xor key
    const int xkey = n & 7;

    for (int k0 = 0; k0 < IN_CH; k0 += 8) {
        const int chunk = k0 >> 3;
        const int xofs  = ((chunk ^ xkey) << 3);
        V16 va, vb;
        va.v = *(const int4*)&xa[xofs];
        vb.v = *(const int4*)&xb[xofs];
        const _Float16* wbase = &Wt[col0 * IN_CH + ((chunk ^ g) << 3)];
        #pragma unroll
        for (int j = 0; j < 8; ++j) {
            V16 w;
            w.v = *(const int4*)&wbase[j * IN_CH];   // j*256 B immediate
            float a = accA[j], b = accB[j];
            a = fdot2(w.h[0], va.h[0], a); b = fdot2(w.h[0], vb.h[0], b);
            a = fdot2(w.h[1], va.h[1], a); b = fdot2(w.h[1], vb.h[1], b);
            a = fdot2(w.h[2], va.h[2], a); b = fdot2(w.h[2], vb.h[2], b);
            a = fdot2(w.h[3], va.h[3], a); b = fdot2(w.h[3], vb.h[3], b);
            accA[j] = a; accB[j] = b;
        }
    }

    float asr[8], adr[8];
    #pragma unroll
    for (int j = 0; j < 8; ++j) {
        asr[j] = a_src[head * OUT_CH + c0 + j];
        adr[j] = a_dst[head * OUT_CH + c0 + j];
    }

    #pragma unroll
    for (int half = 0; half < 2; ++half) {
        const float* acc = half ? accB : accA;
        const int node = node0 + n + half * 32;
        if (node < n_nodes) {
            unsigned u[8];
            #pragma unroll
            for (int j = 0; j < 8; ++j) u[j] = __half_as_ushort(__float2half_rn(acc[j]));
            int4 v = make_int4((int)(u[0] | (u[1] << 16)), (int)(u[2] | (u[3] << 16)),
                               (int)(u[4] | (u[5] << 16)), (int)(u[6] | (u[7] << 16)));
            *(int4*)&h[(size_t)node * HC + col0] = v;
        }
        float ps = 0.f, pd = 0.f;
        #pragma unroll
        for (int j = 0; j < 8; ++j) { ps += acc[j] * asr[j]; pd += acc[j] * adr[j]; }
        ps += __shfl_xor(ps, 1); ps += __shfl_xor(ps, 2);
        pd += __shfl_xor(pd, 1); pd += __shfl_xor(pd, 2);
        if ((g & 3) == 0 && node < n_nodes) {
            alpha_s[node * HEADS + head] = ps;
            alpha_d[node * HEADS + head] = pd;
        }
    }
}

// ---------------------------------------------------------------------------
// Kernel 2: minimal atomic-free scatter. 3 coalesced loads (src,dst,rank) +
// one fire-and-forget 4 B store of the src index into bins4[d*64+rk].
// Separate kernel on purpose: its scattered stores and the hist atomics
// share the vector-memory pipe and ADD when fused (R4: +23 us).
// ---------------------------------------------------------------------------
__global__ void fill_kernel(const int* __restrict__ src, const int* __restrict__ dst,
                            const int* __restrict__ rank,
                            int* __restrict__ bins4, int n_edges, int n_total)
{
    int e = blockIdx.x * blockDim.x + threadIdx.x;
    if (e >= n_total) return;
    int s, d;
    if (e < n_edges) { s = src[e]; d = dst[e]; }
    else             { s = d = e - n_edges; }
    int rk = rank[e];
    if (rk < BIN_CAP) bins4[(size_t)d * BIN_CAP + rk] = s;
}

// ---------------------------------------------------------------------------
// Kernel 3: one wave per node.
// PRELOAD (parallel): lane L reads src idx L (coalesced), gathers
// alpha_s2[s] (64 random 8 B loads in flight), computes p0/p1 =
// exp(leakyrelu(...)); f16-rounds them; butterfly-reduces lsum ONCE; stages
// {src, p01:f16x2} to this wave's LDS slot (one ds_write_b64).
// INNER LOOP (R8): EIGHT edges per wave-instruction. Lane L: subgroup
// q=L>>3 owns edge slot i+q; channel octet c=L&7 (16 B of the 128 B
// h-row). Per 8 edges: 1 ds_read_b64 (8-addr bcast) + 1
// global_load_dwordx4 (64 lanes x 16 B = 8 full rows) + ~20 VALU —
// halves the VMEM issue count vs the 4-edge version (VMEM-pipe bound).
// Epilogue: shfl_xor 8/16/32 combine; lanes 0-7 write 2x float4.
// Rounds of 8 slots (p=0 beyond cnt -> branch-free).
// ---------------------------------------------------------------------------
__global__ __launch_bounds__(256) void node_gather_kernel(
    const int* __restrict__ bins4, const int* __restrict__ deg,
    const float* __restrict__ alpha_s, const float* __restrict__ alpha_d,
    const __half* __restrict__ h, const float* __restrict__ bias,
    float* __restrict__ out, int n_nodes)
{
    __shared__ int2 stage[4][BIN_CAP];   // 2 KB; one 64-slot row per wave
    const int w = threadIdx.x >> 6;
    int node = blockIdx.x * 4 + w;
    if (node >= n_nodes) return;
    const int lane = threadIdx.x & 63;
    int cnt = deg[node];
    if (cnt > BIN_CAP) cnt = BIN_CAP;

    float2 adn = ((const float2*)alpha_d)[node];

    int sreg = 0;
    float p0 = 0.f, p1 = 0.f;
    if (lane < cnt) {
        sreg = bins4[(size_t)node * BIN_CAP + lane];
        float2 a2 = ((const float2*)alpha_s)[sreg];
        float v0 = a2.x + adn.x;
        float v1 = a2.y + adn.y;
        v0 = (v0 > 0.f) ? v0 : NEG_SLOPE * v0;
        v1 = (v1 > 0.f) ? v1 : NEG_SLOPE * v1;
        p0 = __expf(v0);   // shift-invariant softmax; logits O(8): no overflow
        p1 = __expf(v1);
    }

    // f16-round p (so lsum matches the accumulated values exactly)
    unsigned u0 = __half_as_ushort(__float2half_rn(p0));
    unsigned u1 = __half_as_ushort(__float2half_rn(p1));
    float q0 = __half2float(__ushort_as_half((unsigned short)u0));
    float q1 = __half2float(__ushort_as_half((unsigned short)u1));

    // lsum once per node: butterfly over 64 lanes
    #pragma unroll
    for (int off = 1; off < 64; off <<= 1) {
        q0 += __shfl_xor(q0, off);
        q1 += __shfl_xor(q1, off);
    }

    // stage records (one ds_write_b64 per wave)
    stage[w][lane] = make_int2(sreg, (int)((u1 << 16) | u0));
    // same-wave LDS write->read ordering: compiler inserts lgkmcnt wait

    const int q = lane >> 3;                        // edge subgroup 0..7
    const int c = lane & 7;                         // channel octet: ch 8c..8c+7
    const unsigned hshift = (unsigned)(c >> 2) << 4;   // head select: 0 or 16
    const unsigned laneofs = (unsigned)c << 4;      // byte offset in h row (16 B)
    const char* hb = (const char*)h;

    float acc[8] = {0,0,0,0,0,0,0,0};
    for (int i = 0; i < cnt; i += 8) {
        int2 rec = stage[w][i + q];                 // 8-addr 8-lane bcast
        unsigned ofs = ((unsigned)rec.x << 7) + laneofs; // row = 128 B
        int4 hv = *(const int4*)(hb + ofs);         // 8 halves
        float pj = __half2float(__ushort_as_half(
                       (unsigned short)(((unsigned)rec.y) >> hshift)));
        const int* hp = &hv.x;
        #pragma unroll
        for (int k = 0; k < 4; ++k) {
            __half2 h2 = *(__half2*)&hp[k];
            float2 f2 = __half22float2(h2);
            acc[2*k]   += pj * f2.x;                // p=0 beyond cnt
            acc[2*k+1] += pj * f2.y;
        }
    }
    // combine the 8 edge-subsets across subgroups (lanes sharing c)
    #pragma unroll
    for (int k = 0; k < 8; ++k) {
        acc[k] += __shfl_xor(acc[k], 8);
        acc[k] += __shfl_xor(acc[k], 16);
        acc[k] += __shfl_xor(acc[k], 32);
    }

    if (lane < 8) {
        const float lsum = (c >> 2) ? q1 : q0;
        const float inv = 1.f / (lsum + 1e-16f);
        float4 b0 = ((const float4*)bias)[2 * c];
        float4 b1 = ((const float4*)bias)[2 * c + 1];
        float4 o0, o1;
        o0.x = acc[0] * inv + b0.x;  o0.y = acc[1] * inv + b0.y;
        o0.z = acc[2] * inv + b0.z;  o0.w = acc[3] * inv + b0.w;
        o1.x = acc[4] * inv + b1.x;  o1.y = acc[5] * inv + b1.y;
        o1.z = acc[6] * inv + b1.z;  o1.w = acc[7] * inv + b1.w;
        float4* orow = (float4*)out + (size_t)node * (HC / 4);
        orow[2 * c]     = o0;
        orow[2 * c + 1] = o1;
    }
}

// ---------------------------------------------------------------------------
extern "C" void kernel_launch(void* const* d_in, const int* in_sizes, int n_in,
                              void* d_out, int out_size, void* d_ws, size_t ws_size,
                              hipStream_t stream)
{
    const float* x      = (const float*)d_in[0];
    const int*   ei     = (const int*)d_in[1];
    const float* W      = (const float*)d_in[2];
    const float* a_src  = (const float*)d_in[3];
    const float* a_dst  = (const float*)d_in[4];
    const float* bias   = (const float*)d_in[5];
    float* out = (float*)d_out;

    const int n_nodes = in_sizes[0] / IN_CH;        // 50000
    const int n_edges = in_sizes[1] / 2;            // 800000
    const int n_total = n_edges + n_nodes;

    const int* src = ei;             // row 0
    const int* dst = ei + n_edges;   // row 1

    // workspace layout (~33 MB of 268 MB)
    __half* h      = (__half*)d_ws;                              // n*64 f16
    float* alpha_s = (float*)(h + (size_t)n_nodes * HC);         // n*2
    float* alpha_d = alpha_s + (size_t)n_nodes * HEADS;          // n*2
    int* deg       = (int*)(alpha_d + (size_t)n_nodes * HEADS);  // n
    int* rank      = deg + n_nodes;                              // n_total
    int* bins4     = rank + n_total;                             // n*64 int

    const int edge_blocks = (n_total + 255) / 256;
    const int gemm_blocks = (n_nodes + NODE_TILE - 1) / NODE_TILE;

    // 1. zero deg (tiny memset node)
    hipMemsetAsync(deg, 0, (size_t)n_nodes * sizeof(int), stream);

    // 2. mixed grid: gemm+logits (LDS/VALU) || hist->rank (atomic, TA pipe)
    gemm_hist_kernel<<<gemm_blocks + edge_blocks, 256, 0, stream>>>(
        x, W, a_src, a_dst, h, alpha_s, alpha_d,
        dst, deg, rank, n_nodes, n_edges, n_total, gemm_blocks);

    // 3. minimal scatter: src index -> bins
    fill_kernel<<<edge_blocks, 256, 0, stream>>>(
        src, dst, rank, bins4, n_edges, n_total);

    // 4. gather: 8-edge staged-broadcast inner loop; + bias
    int ng_blocks = (n_nodes + 3) / 4;
    node_gather_kernel<<<ng_blocks, 256, 0, stream>>>(
        bins4, deg, alpha_s, alpha_d, h, bias, out, n_nodes);
}

// Round 9
// 148.162 us; speedup vs baseline: 1.2015x; 1.0493x over previous
//
#include <hip/hip_runtime.h>
#include <hip/hip_bf16.h>
#include <hip/hip_fp16.h>
#include <math.h>

#define IN_CH   128
#define OUT_CH  32
#define HEADS   2
#define HC      (HEADS * OUT_CH)   // 64
#define NEG_SLOPE 0.2f

#define NODE_TILE 64
#define LDS_STRIDE 136   // f16: 128 + 8 pad; 272 B rows (16B-aligned b128)

#define BIN_CAP 64       // max deg: Poisson(17), P(>=64) ~ 1e-19/node — safe

// Session ledger (R1-R8): poison fill ~45us (harness, untouchable); hist
// atomic phase ~44us = ~19G atomics/s HW wall (invariant under ILP R3,
// occupancy R4/R5, line layout R7); GEMM rides free inside the atomic
// window (R1/R2 mixed = hist alone); scattered stores ADD to atomics when
// fused (R4 +23us) -> keep fill separate. Gather is latency-bound (issue
// count ~3us worth; 2/4/8-edge variants all equal) -> this round: 2 nodes
// per wave for chain-level ILP.

typedef _Float16 h2_t __attribute__((ext_vector_type(2)));
union V16 { int4 v; h2_t h[4]; };

__device__ __forceinline__ float fdot2(h2_t a, h2_t b, float c) {
#if __has_builtin(__builtin_amdgcn_fdot2)
    return __builtin_amdgcn_fdot2(a, b, c, false);
#else
    return c + (float)a.x * (float)b.x + (float)a.y * (float)b.y;
#endif
}

// ---------------------------------------------------------------------------
// Kernel 1 (mixed grid, exact R1 champion): blocks [0, gemm_blocks) = GEMM
// h = x@W (f16 LDS + v_dot2_f32_f16, 2 nodes/thread) + fused logits.
// Blocks [gemm_blocks, ...) = hist: rank[e] = atomicAdd(deg[d]) — atomic
// return feeds ONLY a coalesced write.
// ---------------------------------------------------------------------------
__global__ __launch_bounds__(256) void gemm_hist_kernel(
    const float* __restrict__ x, const float* __restrict__ W,
    const float* __restrict__ a_src, const float* __restrict__ a_dst,
    __half* __restrict__ h, float* __restrict__ alpha_s, float* __restrict__ alpha_d,
    const int* __restrict__ dst, int* __restrict__ deg, int* __restrict__ rank,
    int n_nodes, int n_edges, int n_total, int gemm_blocks)
{
    const int tid = threadIdx.x;

    if (blockIdx.x >= gemm_blocks) {
        // ---- hist role (no LDS touched) ----
        int e = (blockIdx.x - gemm_blocks) * blockDim.x + tid;
        if (e < n_total) {
            int d = (e < n_edges) ? dst[e] : (e - n_edges);
            rank[e] = atomicAdd(&deg[d], 1);
        }
        return;
    }

    // ---- gemm role ----
    __shared__ _Float16 Wt[HC * LDS_STRIDE];        // [col][k], 17 KB
    __shared__ _Float16 Xs[NODE_TILE * LDS_STRIDE]; // [node][k], 17 KB

    const int node0 = blockIdx.x * NODE_TILE;

    const float4* W4 = (const float4*)W;
    #pragma unroll
    for (int i = 0; i < 8; ++i) {
        int idx4 = tid + i * 256;
        int k  = idx4 >> 4;        // 16 float4 per W row (64 cols)
        int c4 = idx4 & 15;
        float4 v = W4[idx4];
        Wt[(c4 * 4 + 0) * LDS_STRIDE + k] = (_Float16)v.x;
        Wt[(c4 * 4 + 1) * LDS_STRIDE + k] = (_Float16)v.y;
        Wt[(c4 * 4 + 2) * LDS_STRIDE + k] = (_Float16)v.z;
        Wt[(c4 * 4 + 3) * LDS_STRIDE + k] = (_Float16)v.w;
    }

    const float4* X4 = (const float4*)x;
    #pragma unroll
    for (int i = 0; i < 8; ++i) {
        int idx4 = tid + i * 256;
        int r = idx4 >> 5, c4 = idx4 & 31;
        int node = node0 + r;
        float4 v = make_float4(0.f, 0.f, 0.f, 0.f);
        if (node < n_nodes) v = X4[(size_t)node * (IN_CH / 4) + c4];
        _Float16 hv[4] = {(_Float16)v.x, (_Float16)v.y, (_Float16)v.z, (_Float16)v.w};
        *(int2*)&Xs[r * LDS_STRIDE + c4 * 4] = *(int2*)hv;  // 8 B aligned
    }
    __syncthreads();

    const int n    = tid >> 3;        // 0..31  (nodes n and n+32)
    const int g    = tid & 7;
    const int col0 = g * 8;
    const int head = col0 >> 5;
    const int c0   = col0 & 31;

    float accA[8] = {0,0,0,0,0,0,0,0};
    float accB[8] = {0,0,0,0,0,0,0,0};
    const _Float16* xa = &Xs[n * LDS_STRIDE];
    const _Float16* xb = &Xs[(n + 32) * LDS_STRIDE];

    for (int k0 = 0; k0 < IN_CH; k0 += 8) {
        V16 va, vb;
        va.v = *(const int4*)&xa[k0];
        vb.v = *(const int4*)&xb[k0];
        #pragma unroll
        for (int j = 0; j < 8; ++j) {
            V16 w;
            w.v = *(const int4*)&Wt[(col0 + j) * LDS_STRIDE + k0];
            float a = accA[j], b = accB[j];
            a = fdot2(w.h[0], va.h[0], a); b = fdot2(w.h[0], vb.h[0], b);
            a = fdot2(w.h[1], va.h[1], a); b = fdot2(w.h[1], vb.h[1], b);
            a = fdot2(w.h[2], va.h[2], a); b = fdot2(w.h[2], vb.h[2], b);
            a = fdot2(w.h[3], va.h[3], a); b = fdot2(w.h[3], vb.h[3], b);
            accA[j] = a; accB[j] = b;
        }
    }

    float asr[8], adr[8];
    #pragma unroll
    for (int j = 0; j < 8; ++j) {
        asr[j] = a_src[head * OUT_CH + c0 + j];
        adr[j] = a_dst[head * OUT_CH + c0 + j];
    }

    #pragma unroll
    for (int half = 0; half < 2; ++half) {
        const float* acc = half ? accB : accA;
        const int node = node0 + n + half * 32;
        if (node < n_nodes) {
            unsigned u[8];
            #pragma unroll
            for (int j = 0; j < 8; ++j) u[j] = __half_as_ushort(__float2half_rn(acc[j]));
            int4 v = make_int4((int)(u[0] | (u[1] << 16)), (int)(u[2] | (u[3] << 16)),
                               (int)(u[4] | (u[5] << 16)), (int)(u[6] | (u[7] << 16)));
            *(int4*)&h[(size_t)node * HC + col0] = v;
        }
        float ps = 0.f, pd = 0.f;
        #pragma unroll
        for (int j = 0; j < 8; ++j) { ps += acc[j] * asr[j]; pd += acc[j] * adr[j]; }
        ps += __shfl_xor(ps, 1); ps += __shfl_xor(ps, 2);
        pd += __shfl_xor(pd, 1); pd += __shfl_xor(pd, 2);
        if ((g & 3) == 0 && node < n_nodes) {
            alpha_s[node * HEADS + head] = ps;
            alpha_d[node * HEADS + head] = pd;
        }
    }
}

// ---------------------------------------------------------------------------
// Kernel 2: minimal atomic-free scatter. 3 coalesced loads (src,dst,rank) +
// one fire-and-forget 4 B store of the src index into bins4[d*64+rk].
// ---------------------------------------------------------------------------
__global__ void fill_kernel(const int* __restrict__ src, const int* __restrict__ dst,
                            const int* __restrict__ rank,
                            int* __restrict__ bins4, int n_edges, int n_total)
{
    int e = blockIdx.x * blockDim.x + threadIdx.x;
    if (e >= n_total) return;
    int s, d;
    if (e < n_edges) { s = src[e]; d = dst[e]; }
    else             { s = d = e - n_edges; }
    int rk = rank[e];
    if (rk < BIN_CAP) bins4[(size_t)d * BIN_CAP + rk] = s;
}

// ---------------------------------------------------------------------------
// Kernel 3 (R9): TWO nodes per wave (latency-bound phase -> chain ILP).
// Each wave runs two independent preload chains (2 scattered alpha_s
// gathers in flight), stages both nodes' {src,p} records, then an
// interleaved inner loop: per step 2 ds_read_b64 + 2 __half2 loads (A,B
// independent). Loop to max(cntA,cntB); slots beyond a node's cnt have
// staged p=0 (branch-free). Epilogue: shfl_xor(32) per node, float2 writes.
// ---------------------------------------------------------------------------
__global__ __launch_bounds__(256) void node_gather_kernel(
    const int* __restrict__ bins4, const int* __restrict__ deg,
    const float* __restrict__ alpha_s, const float* __restrict__ alpha_d,
    const __half* __restrict__ h, const float* __restrict__ bias,
    float* __restrict__ out, int n_nodes)
{
    __shared__ int2 stageA[4][BIN_CAP];   // 2 KB
    __shared__ int2 stageB[4][BIN_CAP];   // 2 KB
    const int w = threadIdx.x >> 6;
    const int lane = threadIdx.x & 63;
    const int nodeA = blockIdx.x * 8 + w * 2;
    const int nodeB = nodeA + 1;
    if (nodeA >= n_nodes) return;
    const bool hasB = (nodeB < n_nodes);

    int cntA = deg[nodeA]; if (cntA > BIN_CAP) cntA = BIN_CAP;
    int cntB = hasB ? deg[nodeB] : 0; if (cntB > BIN_CAP) cntB = BIN_CAP;

    float2 adnA = ((const float2*)alpha_d)[nodeA];
    float2 adnB = hasB ? ((const float2*)alpha_d)[nodeB] : make_float2(0.f, 0.f);

    // two independent preload chains
    int sregA = 0, sregB = 0;
    float p0A = 0.f, p1A = 0.f, p0B = 0.f, p1B = 0.f;
    if (lane < cntA) sregA = bins4[(size_t)nodeA * BIN_CAP + lane];
    if (lane < cntB) sregB = bins4[(size_t)nodeB * BIN_CAP + lane];
    if (lane < cntA) {
        float2 a2 = ((const float2*)alpha_s)[sregA];
        float v0 = a2.x + adnA.x, v1 = a2.y + adnA.y;
        v0 = (v0 > 0.f) ? v0 : NEG_SLOPE * v0;
        v1 = (v1 > 0.f) ? v1 : NEG_SLOPE * v1;
        p0A = __expf(v0); p1A = __expf(v1);
    }
    if (lane < cntB) {
        float2 a2 = ((const float2*)alpha_s)[sregB];
        float v0 = a2.x + adnB.x, v1 = a2.y + adnB.y;
        v0 = (v0 > 0.f) ? v0 : NEG_SLOPE * v0;
        v1 = (v1 > 0.f) ? v1 : NEG_SLOPE * v1;
        p0B = __expf(v0); p1B = __expf(v1);
    }

    // f16-round p (so lsum matches the accumulated values exactly)
    unsigned u0A = __half_as_ushort(__float2half_rn(p0A));
    unsigned u1A = __half_as_ushort(__float2half_rn(p1A));
    unsigned u0B = __half_as_ushort(__float2half_rn(p0B));
    unsigned u1B = __half_as_ushort(__float2half_rn(p1B));
    float q0A = __half2float(__ushort_as_half((unsigned short)u0A));
    float q1A = __half2float(__ushort_as_half((unsigned short)u1A));
    float q0B = __half2float(__ushort_as_half((unsigned short)u0B));
    float q1B = __half2float(__ushort_as_half((unsigned short)u1B));

    // lsum butterflies (4 values, 24 shfl)
    #pragma unroll
    for (int off = 1; off < 64; off <<= 1) {
        q0A += __shfl_xor(q0A, off);
        q1A += __shfl_xor(q1A, off);
        q0B += __shfl_xor(q0B, off);
        q1B += __shfl_xor(q1B, off);
    }

    stageA[w][lane] = make_int2(sregA, (int)((u1A << 16) | u0A));
    stageB[w][lane] = make_int2(sregB, (int)((u1B << 16) | u0B));
    // same-wave LDS write->read ordering: compiler inserts lgkmcnt wait

    const int eh = lane >> 5;                       // which of the 2 edges
    const int c2 = lane & 31;                       // channel pair
    const unsigned hshift = (unsigned)(c2 >> 4) << 4;  // head select: 0 or 16
    const unsigned laneofs = (unsigned)c2 << 2;     // byte offset in h row
    const char* hb = (const char*)h;

    const int cntMax = cntA > cntB ? cntA : cntB;
    float axA = 0.f, ayA = 0.f, axB = 0.f, ayB = 0.f;
    for (int i = 0; i < cntMax; i += 8) {
        #pragma unroll
        for (int j = 0; j < 4; ++j) {
            int2 recA = stageA[w][i + 2 * j + eh];  // 2-addr half-wave bcast
            int2 recB = stageB[w][i + 2 * j + eh];
            unsigned ofsA = ((unsigned)recA.x << 7) + laneofs; // row = 128 B
            unsigned ofsB = ((unsigned)recB.x << 7) + laneofs;
            __half2 hvA = *(const __half2*)(hb + ofsA);
            __half2 hvB = *(const __half2*)(hb + ofsB);
            float2 fA = __half22float2(hvA);
            float2 fB = __half22float2(hvB);
            float pA = __half2float(__ushort_as_half(
                           (unsigned short)(((unsigned)recA.y) >> hshift)));
            float pB = __half2float(__ushort_as_half(
                           (unsigned short)(((unsigned)recB.y) >> hshift)));
            axA += pA * fA.x;  ayA += pA * fA.y;    // p=0 beyond cnt
            axB += pB * fB.x;  ayB += pB * fB.y;
        }
    }
    // combine the two edge-subsets (even/odd slots) across half-waves
    axA += __shfl_xor(axA, 32);  ayA += __shfl_xor(ayA, 32);
    axB += __shfl_xor(axB, 32);  ayB += __shfl_xor(ayB, 32);

    if (lane < 32) {
        float2 b2 = ((const float2*)bias)[c2];
        {
            const float lsum = (c2 >> 4) ? q1A : q0A;
            const float inv = 1.f / (lsum + 1e-16f);
            float2 o;
            o.x = axA * inv + b2.x;
            o.y = ayA * inv + b2.y;
            ((float2*)out)[(size_t)nodeA * (HC / 2) + c2] = o;
        }
        if (hasB) {
            const float lsum = (c2 >> 4) ? q1B : q0B;
            const float inv = 1.f / (lsum + 1e-16f);
            float2 o;
            o.x = axB * inv + b2.x;
            o.y = ayB * inv + b2.y;
            ((float2*)out)[(size_t)nodeB * (HC / 2) + c2] = o;
        }
    }
}

// ---------------------------------------------------------------------------
extern "C" void kernel_launch(void* const* d_in, const int* in_sizes, int n_in,
                              void* d_out, int out_size, void* d_ws, size_t ws_size,
                              hipStream_t stream)
{
    const float* x      = (const float*)d_in[0];
    const int*   ei     = (const int*)d_in[1];
    const float* W      = (const float*)d_in[2];
    const float* a_src  = (const float*)d_in[3];
    const float* a_dst  = (const float*)d_in[4];
    const float* bias   = (const float*)d_in[5];
    float* out = (float*)d_out;

    const int n_nodes = in_sizes[0] / IN_CH;        // 50000
    const int n_edges = in_sizes[1] / 2;            // 800000
    const int n_total = n_edges + n_nodes;

    const int* src = ei;             // row 0
    const int* dst = ei + n_edges;   // row 1

    // workspace layout (~33 MB of 268 MB)
    __half* h      = (__half*)d_ws;                              // n*64 f16
    float* alpha_s = (float*)(h + (size_t)n_nodes * HC);         // n*2
    float* alpha_d = alpha_s + (size_t)n_nodes * HEADS;          // n*2
    int* deg       = (int*)(alpha_d + (size_t)n_nodes * HEADS);  // n
    int* rank      = deg + n_nodes;                              // n_total
    int* bins4     = rank + n_total;                             // n*64 int

    const int edge_blocks = (n_total + 255) / 256;
    const int gemm_blocks = (n_nodes + NODE_TILE - 1) / NODE_TILE;

    // 1. zero deg (tiny memset node)
    hipMemsetAsync(deg, 0, (size_t)n_nodes * sizeof(int), stream);

    // 2. mixed grid: gemm+logits (long pole rides free) || hist->rank
    gemm_hist_kernel<<<gemm_blocks + edge_blocks, 256, 0, stream>>>(
        x, W, a_src, a_dst, h, alpha_s, alpha_d,
        dst, deg, rank, n_nodes, n_edges, n_total, gemm_blocks);

    // 3. minimal scatter: src index -> bins
    fill_kernel<<<edge_blocks, 256, 0, stream>>>(
        src, dst, rank, bins4, n_edges, n_total);

    // 4. gather: 2 nodes/wave, interleaved chains
    int ng_blocks = (n_nodes + 7) / 8;
    node_gather_kernel<<<ng_blocks, 256, 0, stream>>>(
        bins4, deg, alpha_s, alpha_d, h, bias, out, n_nodes);
}